// Round 3
// baseline (3441.507 us; speedup 1.0000x reference)
//
#include <hip/hip_runtime.h>

#define TPB 128

// ---------------- fast tanh: (e^{2x}-1)/(e^{2x}+1), clamp avoids inf*0 ----------------
__device__ __forceinline__ float fast_tanh(float v) {
    float vc = fminf(v, 15.0f);                 // tanh(15) == 1.0f in fp32
    float e  = __expf(vc + vc);                 // v_exp_f32 path
    float r  = __builtin_amdgcn_rcpf(e + 1.0f); // v_rcp_f32, ~1e-7 rel err
    return (e - 1.0f) * r;
}

__device__ __forceinline__ void load64(float (&z)[64], const float* __restrict__ p) {
    const float4* p4 = (const float4*)p;
#pragma unroll
    for (int q = 0; q < 16; ++q) {
        float4 b = p4[q];
        z[4*q+0] = b.x; z[4*q+1] = b.y; z[4*q+2] = b.z; z[4*q+3] = b.w;
    }
}

__device__ __forceinline__ void zero64(float (&z)[64]) {
#pragma unroll
    for (int j = 0; j < 64; ++j) z[j] = 0.0f;
}

// z[0..63] += sum_k buf[k][tid] * W[k*64 + j]   (W uniform -> SGPR weight stream)
__device__ __forceinline__ void mv64(float (&z)[64], const float* __restrict__ W,
                                     float (*buf)[TPB], int tid) {
#pragma unroll 2
    for (int k = 0; k < 64; ++k) {
        float ak = buf[k][tid];
        const float4* w4 = (const float4*)(W + (k << 6));
#pragma unroll
        for (int q = 0; q < 16; ++q) {
            float4 w = w4[q];
            z[4*q+0] = fmaf(ak, w.x, z[4*q+0]);
            z[4*q+1] = fmaf(ak, w.y, z[4*q+1]);
            z[4*q+2] = fmaf(ak, w.z, z[4*q+2]);
            z[4*q+3] = fmaf(ak, w.w, z[4*q+3]);
        }
    }
}

// coupling net: 2 -> 125 (relu) -> 125 (tanh) -> 2.  h1 recomputed on the fly.
__device__ __forceinline__ void coupling_net(float u0, float u1,
        const float* __restrict__ cw1, const float* __restrict__ cb1,
        const float* __restrict__ wsf, const float* __restrict__ cb3,
        float& o0, float& o1) {
    const float* cb2p = wsf + 16000;   // [128]
    const float* cw3p = wsf + 16128;   // [128][2]
    float a0 = cb3[0], a1 = cb3[1];
#pragma unroll 1
    for (int half = 0; half < 2; ++half) {
        float z[64];
        load64(z, cb2p + half * 64);
#pragma unroll 2
        for (int k = 0; k < 125; ++k) {
            float h = fmaf(u1, cw1[125 + k], fmaf(u0, cw1[k], cb1[k]));
            h = fmaxf(h, 0.0f);
            const float4* w4 = (const float4*)(wsf + k * 128 + half * 64); // cw2 padded [125][128]
#pragma unroll
            for (int q = 0; q < 16; ++q) {
                float4 w = w4[q];
                z[4*q+0] = fmaf(h, w.x, z[4*q+0]);
                z[4*q+1] = fmaf(h, w.y, z[4*q+1]);
                z[4*q+2] = fmaf(h, w.z, z[4*q+2]);
                z[4*q+3] = fmaf(h, w.w, z[4*q+3]);
            }
        }
#pragma unroll
        for (int j = 0; j < 64; ++j) {
            float t = fast_tanh(z[j]);
            int jj = (half << 6) + j;
            a0 = fmaf(t, cw3p[2*jj+0], a0);
            a1 = fmaf(t, cw3p[2*jj+1], a1);
        }
    }
    o0 = a0; o1 = a1;
}

// pack: ws = [ cw2p 125x128 | cb2p 128 | cw3p 128x2 | hw2T..hw5T 4x64x64 ]  (32768 floats)
__global__ void pack_weights(const float* __restrict__ cw2, const float* __restrict__ cb2,
                             const float* __restrict__ cw3,
                             const float* __restrict__ hw2, const float* __restrict__ hw3,
                             const float* __restrict__ hw4, const float* __restrict__ hw5,
                             float* __restrict__ ws) {
    int i = blockIdx.x * 256 + threadIdx.x;
    if (i < 16000) { int k = i >> 7, j = i & 127; ws[i] = (j < 125) ? cw2[k * 125 + j] : 0.0f; }
    if (i < 128)   { ws[16000 + i] = (i < 125) ? cb2[i] : 0.0f; }
    if (i < 256)   { int j = i >> 1, c = i & 1; ws[16128 + i] = (j < 125) ? cw3[j * 2 + c] : 0.0f; }
    if (i < 16384) {
        int m = i >> 12, r = (i >> 6) & 63, c = i & 63;
        const float* w = (m == 0) ? hw2 : ((m == 1) ? hw3 : ((m == 2) ? hw4 : hw5));
        ws[16384 + i] = w[c * 64 + r];   // wT[m][r][c] = w[c][r]
    }
}

// launch_bounds(128,3): cap 170 VGPR -> 10 waves/CU (LDS 32KB/block allows 5 blocks).
__global__ __launch_bounds__(TPB, 3) void pnn_main(
        const float* __restrict__ x,
        const float* __restrict__ cw1, const float* __restrict__ cb1,
        const float* __restrict__ cb3,
        const float* __restrict__ hw1, const float* __restrict__ hb1,
        const float* __restrict__ hw2, const float* __restrict__ hb2,
        const float* __restrict__ hw3, const float* __restrict__ hb3,
        const float* __restrict__ hw4, const float* __restrict__ hb4,
        const float* __restrict__ hw5, const float* __restrict__ hb5,
        const float* __restrict__ hw6,
        const float* __restrict__ S, const float* __restrict__ dt_q,
        const float* __restrict__ dt_p, const float* __restrict__ alpha_p,
        const float* __restrict__ wsf,
        float* __restrict__ out, int nrows) {
    __shared__ float buf[64][TPB];    // thread-private column: no barriers anywhere
    const int tid = threadIdx.x;
    const int row = blockIdx.x * TPB + tid;
    if (row >= nrows) return;

    float4 xv = ((const float4*)x)[row];

    // ---- theta = [x1, x2 + coupling(x1)] ----
    float c0, c1;
    coupling_net(xv.x, xv.y, cw1, cb1, wsf, cb3, c0, c1);
    float th0 = xv.x, th1 = xv.y, th2 = xv.z + c0, th3 = xv.w + c1;

    float z[64];
    unsigned tpk[64];   // bf16(t3) | bf16(t4)<<16 — backward tanh' state, 64 regs not 128

    // ---- H forward L1: z1 = theta @ hw1 + hb1, relu ----
    load64(z, hb1);
    {
        float tin[4] = {th0, th1, th2, th3};
#pragma unroll
        for (int k = 0; k < 4; ++k) {
            float ak = tin[k];
            const float4* w4 = (const float4*)(hw1 + (k << 6));
#pragma unroll
            for (int q = 0; q < 16; ++q) {
                float4 w = w4[q];
                z[4*q+0] = fmaf(ak, w.x, z[4*q+0]);
                z[4*q+1] = fmaf(ak, w.y, z[4*q+1]);
                z[4*q+2] = fmaf(ak, w.z, z[4*q+2]);
                z[4*q+3] = fmaf(ak, w.w, z[4*q+3]);
            }
        }
    }
    unsigned m1lo = 0, m1hi = 0;
#pragma unroll
    for (int j = 0; j < 64; ++j) {
        bool p = z[j] > 0.0f;
        unsigned bit = p ? 1u : 0u;
        if (j < 32) m1lo |= bit << j; else m1hi |= bit << (j - 32);
        buf[j][tid] = p ? z[j] : 0.0f;
    }

    // ---- L2: relu ----
    load64(z, hb2);
    mv64(z, hw2, buf, tid);
    unsigned m2lo = 0, m2hi = 0;
#pragma unroll
    for (int j = 0; j < 64; ++j) {
        bool p = z[j] > 0.0f;
        unsigned bit = p ? 1u : 0u;
        if (j < 32) m2lo |= bit << j; else m2hi |= bit << (j - 32);
        buf[j][tid] = p ? z[j] : 0.0f;
    }

    // ---- L3: tanh (t3 -> bf16 low half of tpk) ----
    load64(z, hb3);
    mv64(z, hw3, buf, tid);
#pragma unroll
    for (int j = 0; j < 64; ++j) {
        float t = fast_tanh(z[j]);
        buf[j][tid] = t;
        tpk[j] = (__float_as_uint(t) + 0x8000u) >> 16;   // rounded bf16
    }

    // ---- L4: tanh (t4 -> bf16 high half of tpk) ----
    load64(z, hb4);
    mv64(z, hw4, buf, tid);
#pragma unroll
    for (int j = 0; j < 64; ++j) {
        float t = fast_tanh(z[j]);
        buf[j][tid] = t;
        tpk[j] = (tpk[j] & 0xFFFFu) | ((__float_as_uint(t) + 0x8000u) & 0xFFFF0000u);
    }

    // ---- L5: g5 = hw6 * (1 - tanh(z5)^2) directly ----
    load64(z, hb5);
    mv64(z, hw5, buf, tid);
#pragma unroll
    for (int j = 0; j < 64; ++j) {
        float t5 = fast_tanh(z[j]);
        buf[j][tid] = hw6[j] * fmaf(-t5, t5, 1.0f);
    }

    const float* hw2T = wsf + 16384;
    const float* hw3T = hw2T + 4096;
    const float* hw4T = hw3T + 4096;
    const float* hw5T = hw4T + 4096;

    // ---- B54: g4 = (g5 @ hw5T) * (1 - t4^2) ----
    zero64(z);
    mv64(z, hw5T, buf, tid);
#pragma unroll
    for (int j = 0; j < 64; ++j) {
        float t4 = __uint_as_float(tpk[j] & 0xFFFF0000u);
        buf[j][tid] = z[j] * fmaf(-t4, t4, 1.0f);
    }

    // ---- B43: g3 = (g4 @ hw4T) * (1 - t3^2) ----
    zero64(z);
    mv64(z, hw4T, buf, tid);
#pragma unroll
    for (int j = 0; j < 64; ++j) {
        float t3 = __uint_as_float(tpk[j] << 16);
        buf[j][tid] = z[j] * fmaf(-t3, t3, 1.0f);
    }

    // ---- B32: g2 = (g3 @ hw3T) * relu'(z2) ----
    zero64(z);
    mv64(z, hw3T, buf, tid);
#pragma unroll
    for (int j = 0; j < 64; ++j) {
        bool p = (j < 32) ? ((m2lo >> j) & 1u) : ((m2hi >> (j - 32)) & 1u);
        buf[j][tid] = p ? z[j] : 0.0f;
    }

    // ---- B21 + dH: g1 = (g2 @ hw2T) * relu'(z1);  dH = g1 @ hw1T ----
    zero64(z);
    mv64(z, hw2T, buf, tid);
    float dH0 = 0, dH1 = 0, dH2 = 0, dH3 = 0;
#pragma unroll
    for (int j = 0; j < 64; ++j) {
        bool p = (j < 32) ? ((m1lo >> j) & 1u) : ((m1hi >> (j - 32)) & 1u);
        float g = p ? z[j] : 0.0f;
        dH0 = fmaf(g, hw1[j],       dH0);
        dH1 = fmaf(g, hw1[64 + j],  dH1);
        dH2 = fmaf(g, hw1[128 + j], dH2);
        dH3 = fmaf(g, hw1[192 + j], dH3);
    }

    // ---- epilogue: symplectic-ish update + inverse coupling ----
    float s01 = S[1] - S[4],  s02 = S[2]  - S[8],  s03 = S[3]  - S[12];
    float s10 = -s01,         s12 = S[6]  - S[9],  s13 = S[7]  - S[13];
    float s23 = S[11] - S[14];
    float s32 = -s23;

    float al = alpha_p[0], dq = dt_q[0], dp = dt_p[0];
    float r10 = th1 * s01 + th2 * s02 + th3 * s03;
    float r11 = th0 * s10 + th2 * s12 + th3 * s13;
    float r20 = th0 * s02 + th1 * s12 + th3 * s32;
    float r21 = th0 * s03 + th1 * s13 + th2 * s23;

    float dz10 = dH2 * dq + al * r10;
    float dz11 = dH3 * dq + al * r11;
    float dz20 = -dH0 * dp + al * r20;
    float dz21 = -dH1 * dp + al * r21;

    float p0 = th0 + 0.1f * dz10;
    float p1 = th1 + 0.1f * dz11;
    float p2 = th2 + 0.1f * dz20;
    float p3 = th3 + 0.1f * dz21;

    float d0, d1;
    coupling_net(p0, p1, cw1, cb1, wsf, cb3, d0, d1);

    ((float4*)out)[row] = make_float4(p0, p1, p2 - d0, p3 - d1);
}

extern "C" void kernel_launch(void* const* d_in, const int* in_sizes, int n_in,
                              void* d_out, int out_size, void* d_ws, size_t ws_size,
                              hipStream_t stream) {
    const float* x   = (const float*)d_in[0];
    const float* cw1 = (const float*)d_in[1];
    const float* cb1 = (const float*)d_in[2];
    const float* cw2 = (const float*)d_in[3];
    const float* cb2 = (const float*)d_in[4];
    const float* cw3 = (const float*)d_in[5];
    const float* cb3 = (const float*)d_in[6];
    const float* hw1 = (const float*)d_in[7];
    const float* hb1 = (const float*)d_in[8];
    const float* hw2 = (const float*)d_in[9];
    const float* hb2 = (const float*)d_in[10];
    const float* hw3 = (const float*)d_in[11];
    const float* hb3 = (const float*)d_in[12];
    const float* hw4 = (const float*)d_in[13];
    const float* hb4 = (const float*)d_in[14];
    const float* hw5 = (const float*)d_in[15];
    const float* hb5 = (const float*)d_in[16];
    const float* hw6 = (const float*)d_in[17];
    const float* S   = (const float*)d_in[19];
    const float* dtq = (const float*)d_in[20];
    const float* dtp = (const float*)d_in[21];
    const float* al  = (const float*)d_in[22];
    float* ws  = (float*)d_ws;
    float* out = (float*)d_out;
    int nrows = in_sizes[0] / 4;

    pack_weights<<<64, 256, 0, stream>>>(cw2, cb2, cw3, hw2, hw3, hw4, hw5, ws);
    int grid = (nrows + TPB - 1) / TPB;
    pnn_main<<<grid, TPB, 0, stream>>>(x, cw1, cb1, cb3, hw1, hb1, hw2, hb2, hw3, hb3,
                                       hw4, hb4, hw5, hb5, hw6,
                                       S, dtq, dtp, al, ws, out, nrows);
}

// Round 4
// 1960.858 us; speedup vs baseline: 1.7551x; 1.7551x over previous
//
#include <hip/hip_runtime.h>

#define TPB 256

// ---------------- fast tanh: (e^{2x}-1)/(e^{2x}+1), clamp avoids inf*0 ----------------
__device__ __forceinline__ float fast_tanh(float v) {
    float vc = fminf(v, 15.0f);                 // tanh(15) == 1.0f in fp32
    float e  = __expf(vc + vc);                 // v_exp_f32 path
    float r  = __builtin_amdgcn_rcpf(e + 1.0f); // v_rcp_f32, ~1e-7 rel err
    return (e - 1.0f) * r;
}

__device__ __forceinline__ void load64(float (&z)[64], const float* __restrict__ p) {
    const float4* p4 = (const float4*)p;
#pragma unroll
    for (int q = 0; q < 16; ++q) {
        float4 b = p4[q];
        z[4*q+0] = b.x; z[4*q+1] = b.y; z[4*q+2] = b.z; z[4*q+3] = b.w;
    }
}

__device__ __forceinline__ void zero64(float (&z)[64]) {
#pragma unroll
    for (int j = 0; j < 64; ++j) z[j] = 0.0f;
}

// z[0..63] += sum_k buf[k][tid] * W[k*64 + j]   (W uniform -> SGPR weight stream)
__device__ __forceinline__ void mv64(float (&z)[64], const float* __restrict__ W,
                                     float (*buf)[TPB], int tid) {
#pragma unroll 2
    for (int k = 0; k < 64; ++k) {
        float ak = buf[k][tid];
        const float4* w4 = (const float4*)(W + (k << 6));
#pragma unroll
        for (int q = 0; q < 16; ++q) {
            float4 w = w4[q];
            z[4*q+0] = fmaf(ak, w.x, z[4*q+0]);
            z[4*q+1] = fmaf(ak, w.y, z[4*q+1]);
            z[4*q+2] = fmaf(ak, w.z, z[4*q+2]);
            z[4*q+3] = fmaf(ak, w.w, z[4*q+3]);
        }
    }
}

// coupling net: 2 -> 125 (relu) -> 125 (tanh) -> 2.  h1 recomputed on the fly.
__device__ __forceinline__ void coupling_net(float u0, float u1,
        const float* __restrict__ cw1, const float* __restrict__ cb1,
        const float* __restrict__ wsf, const float* __restrict__ cb3,
        float& o0, float& o1) {
    const float* cb2p = wsf + 16000;   // [128]
    const float* cw3p = wsf + 16128;   // [128][2]
    float a0 = cb3[0], a1 = cb3[1];
#pragma unroll 1
    for (int half = 0; half < 2; ++half) {
        float z[64];
        load64(z, cb2p + half * 64);
#pragma unroll 2
        for (int k = 0; k < 125; ++k) {
            float h = fmaf(u1, cw1[125 + k], fmaf(u0, cw1[k], cb1[k]));
            h = fmaxf(h, 0.0f);
            const float4* w4 = (const float4*)(wsf + k * 128 + half * 64); // cw2 padded [125][128]
#pragma unroll
            for (int q = 0; q < 16; ++q) {
                float4 w = w4[q];
                z[4*q+0] = fmaf(h, w.x, z[4*q+0]);
                z[4*q+1] = fmaf(h, w.y, z[4*q+1]);
                z[4*q+2] = fmaf(h, w.z, z[4*q+2]);
                z[4*q+3] = fmaf(h, w.w, z[4*q+3]);
            }
        }
#pragma unroll
        for (int j = 0; j < 64; ++j) {
            float t = fast_tanh(z[j]);
            int jj = (half << 6) + j;
            a0 = fmaf(t, cw3p[2*jj+0], a0);
            a1 = fmaf(t, cw3p[2*jj+1], a1);
        }
    }
    o0 = a0; o1 = a1;
}

// pack: ws = [ cw2p 125x128 | cb2p 128 | cw3p 128x2 | hw2T..hw5T 4x64x64 ]  (32768 floats)
__global__ void pack_weights(const float* __restrict__ cw2, const float* __restrict__ cb2,
                             const float* __restrict__ cw3,
                             const float* __restrict__ hw2, const float* __restrict__ hw3,
                             const float* __restrict__ hw4, const float* __restrict__ hw5,
                             float* __restrict__ ws) {
    int i = blockIdx.x * 256 + threadIdx.x;
    if (i < 16000) { int k = i >> 7, j = i & 127; ws[i] = (j < 125) ? cw2[k * 125 + j] : 0.0f; }
    if (i < 128)   { ws[16000 + i] = (i < 125) ? cb2[i] : 0.0f; }
    if (i < 256)   { int j = i >> 1, c = i & 1; ws[16128 + i] = (j < 125) ? cw3[j * 2 + c] : 0.0f; }
    if (i < 16384) {
        int m = i >> 12, r = (i >> 6) & 63, c = i & 63;
        const float* w = (m == 0) ? hw2 : ((m == 1) ? hw3 : ((m == 2) ? hw4 : hw5));
        ws[16384 + i] = w[c * 64 + r];   // wT[m][r][c] = w[c][r]
    }
}

// (256,2): 2 waves/EU min -> 256 unified VGPR+AGPR budget per wave.
// Live state: z[64] + tpk[64] + ~25 misc = ~153 -> fits, zero scratch expected.
__global__ __launch_bounds__(TPB, 2) void pnn_main(
        const float* __restrict__ x,
        const float* __restrict__ cw1, const float* __restrict__ cb1,
        const float* __restrict__ cb3,
        const float* __restrict__ hw1, const float* __restrict__ hb1,
        const float* __restrict__ hw2, const float* __restrict__ hb2,
        const float* __restrict__ hw3, const float* __restrict__ hb3,
        const float* __restrict__ hw4, const float* __restrict__ hb4,
        const float* __restrict__ hw5, const float* __restrict__ hb5,
        const float* __restrict__ hw6,
        const float* __restrict__ S, const float* __restrict__ dt_q,
        const float* __restrict__ dt_p, const float* __restrict__ alpha_p,
        const float* __restrict__ wsf,
        float* __restrict__ out, int nrows) {
    __shared__ float buf[64][TPB];    // thread-private column: no barriers anywhere
    const int tid = threadIdx.x;
    const int row = blockIdx.x * TPB + tid;
    if (row >= nrows) return;

    float4 xv = ((const float4*)x)[row];

    // ---- theta = [x1, x2 + coupling(x1)] ----
    float c0, c1;
    coupling_net(xv.x, xv.y, cw1, cb1, wsf, cb3, c0, c1);
    float th0 = xv.x, th1 = xv.y, th2 = xv.z + c0, th3 = xv.w + c1;

    float z[64];
    unsigned tpk[64];   // bf16(t3) | bf16(t4)<<16 — backward tanh' state, 64 regs not 128

    // ---- H forward L1: z1 = theta @ hw1 + hb1, relu ----
    load64(z, hb1);
    {
        float tin[4] = {th0, th1, th2, th3};
#pragma unroll
        for (int k = 0; k < 4; ++k) {
            float ak = tin[k];
            const float4* w4 = (const float4*)(hw1 + (k << 6));
#pragma unroll
            for (int q = 0; q < 16; ++q) {
                float4 w = w4[q];
                z[4*q+0] = fmaf(ak, w.x, z[4*q+0]);
                z[4*q+1] = fmaf(ak, w.y, z[4*q+1]);
                z[4*q+2] = fmaf(ak, w.z, z[4*q+2]);
                z[4*q+3] = fmaf(ak, w.w, z[4*q+3]);
            }
        }
    }
    unsigned m1lo = 0, m1hi = 0;
#pragma unroll
    for (int j = 0; j < 64; ++j) {
        bool p = z[j] > 0.0f;
        unsigned bit = p ? 1u : 0u;
        if (j < 32) m1lo |= bit << j; else m1hi |= bit << (j - 32);
        buf[j][tid] = p ? z[j] : 0.0f;
    }

    // ---- L2: relu ----
    load64(z, hb2);
    mv64(z, hw2, buf, tid);
    unsigned m2lo = 0, m2hi = 0;
#pragma unroll
    for (int j = 0; j < 64; ++j) {
        bool p = z[j] > 0.0f;
        unsigned bit = p ? 1u : 0u;
        if (j < 32) m2lo |= bit << j; else m2hi |= bit << (j - 32);
        buf[j][tid] = p ? z[j] : 0.0f;
    }

    // ---- L3: tanh (t3 -> bf16 low half of tpk) ----
    load64(z, hb3);
    mv64(z, hw3, buf, tid);
#pragma unroll
    for (int j = 0; j < 64; ++j) {
        float t = fast_tanh(z[j]);
        buf[j][tid] = t;
        tpk[j] = (__float_as_uint(t) + 0x8000u) >> 16;   // rounded bf16
    }

    // ---- L4: tanh (t4 -> bf16 high half of tpk) ----
    load64(z, hb4);
    mv64(z, hw4, buf, tid);
#pragma unroll
    for (int j = 0; j < 64; ++j) {
        float t = fast_tanh(z[j]);
        buf[j][tid] = t;
        tpk[j] = (tpk[j] & 0xFFFFu) | ((__float_as_uint(t) + 0x8000u) & 0xFFFF0000u);
    }

    // ---- L5: g5 = hw6 * (1 - tanh(z5)^2) directly ----
    load64(z, hb5);
    mv64(z, hw5, buf, tid);
#pragma unroll
    for (int j = 0; j < 64; ++j) {
        float t5 = fast_tanh(z[j]);
        buf[j][tid] = hw6[j] * fmaf(-t5, t5, 1.0f);
    }

    const float* hw2T = wsf + 16384;
    const float* hw3T = hw2T + 4096;
    const float* hw4T = hw3T + 4096;
    const float* hw5T = hw4T + 4096;

    // ---- B54: g4 = (g5 @ hw5T) * (1 - t4^2) ----
    zero64(z);
    mv64(z, hw5T, buf, tid);
#pragma unroll
    for (int j = 0; j < 64; ++j) {
        float t4 = __uint_as_float(tpk[j] & 0xFFFF0000u);
        buf[j][tid] = z[j] * fmaf(-t4, t4, 1.0f);
    }

    // ---- B43: g3 = (g4 @ hw4T) * (1 - t3^2) ----
    zero64(z);
    mv64(z, hw4T, buf, tid);
#pragma unroll
    for (int j = 0; j < 64; ++j) {
        float t3 = __uint_as_float(tpk[j] << 16);
        buf[j][tid] = z[j] * fmaf(-t3, t3, 1.0f);
    }

    // ---- B32: g2 = (g3 @ hw3T) * relu'(z2) ----
    zero64(z);
    mv64(z, hw3T, buf, tid);
#pragma unroll
    for (int j = 0; j < 64; ++j) {
        bool p = (j < 32) ? ((m2lo >> j) & 1u) : ((m2hi >> (j - 32)) & 1u);
        buf[j][tid] = p ? z[j] : 0.0f;
    }

    // ---- B21 + dH: g1 = (g2 @ hw2T) * relu'(z1);  dH = g1 @ hw1T ----
    zero64(z);
    mv64(z, hw2T, buf, tid);
    float dH0 = 0, dH1 = 0, dH2 = 0, dH3 = 0;
#pragma unroll
    for (int j = 0; j < 64; ++j) {
        bool p = (j < 32) ? ((m1lo >> j) & 1u) : ((m1hi >> (j - 32)) & 1u);
        float g = p ? z[j] : 0.0f;
        dH0 = fmaf(g, hw1[j],       dH0);
        dH1 = fmaf(g, hw1[64 + j],  dH1);
        dH2 = fmaf(g, hw1[128 + j], dH2);
        dH3 = fmaf(g, hw1[192 + j], dH3);
    }

    // ---- epilogue: symplectic-ish update + inverse coupling ----
    float s01 = S[1] - S[4],  s02 = S[2]  - S[8],  s03 = S[3]  - S[12];
    float s10 = -s01,         s12 = S[6]  - S[9],  s13 = S[7]  - S[13];
    float s23 = S[11] - S[14];
    float s32 = -s23;

    float al = alpha_p[0], dq = dt_q[0], dp = dt_p[0];
    float r10 = th1 * s01 + th2 * s02 + th3 * s03;
    float r11 = th0 * s10 + th2 * s12 + th3 * s13;
    float r20 = th0 * s02 + th1 * s12 + th3 * s32;
    float r21 = th0 * s03 + th1 * s13 + th2 * s23;

    float dz10 = dH2 * dq + al * r10;
    float dz11 = dH3 * dq + al * r11;
    float dz20 = -dH0 * dp + al * r20;
    float dz21 = -dH1 * dp + al * r21;

    float p0 = th0 + 0.1f * dz10;
    float p1 = th1 + 0.1f * dz11;
    float p2 = th2 + 0.1f * dz20;
    float p3 = th3 + 0.1f * dz21;

    float d0, d1;
    coupling_net(p0, p1, cw1, cb1, wsf, cb3, d0, d1);

    ((float4*)out)[row] = make_float4(p0, p1, p2 - d0, p3 - d1);
}

extern "C" void kernel_launch(void* const* d_in, const int* in_sizes, int n_in,
                              void* d_out, int out_size, void* d_ws, size_t ws_size,
                              hipStream_t stream) {
    const float* x   = (const float*)d_in[0];
    const float* cw1 = (const float*)d_in[1];
    const float* cb1 = (const float*)d_in[2];
    const float* cw2 = (const float*)d_in[3];
    const float* cb2 = (const float*)d_in[4];
    const float* cw3 = (const float*)d_in[5];
    const float* cb3 = (const float*)d_in[6];
    const float* hw1 = (const float*)d_in[7];
    const float* hb1 = (const float*)d_in[8];
    const float* hw2 = (const float*)d_in[9];
    const float* hb2 = (const float*)d_in[10];
    const float* hw3 = (const float*)d_in[11];
    const float* hb3 = (const float*)d_in[12];
    const float* hw4 = (const float*)d_in[13];
    const float* hb4 = (const float*)d_in[14];
    const float* hw5 = (const float*)d_in[15];
    const float* hb5 = (const float*)d_in[16];
    const float* hw6 = (const float*)d_in[17];
    const float* S   = (const float*)d_in[19];
    const float* dtq = (const float*)d_in[20];
    const float* dtp = (const float*)d_in[21];
    const float* al  = (const float*)d_in[22];
    float* ws  = (float*)d_ws;
    float* out = (float*)d_out;
    int nrows = in_sizes[0] / 4;

    pack_weights<<<64, 256, 0, stream>>>(cw2, cb2, cw3, hw2, hw3, hw4, hw5, ws);
    int grid = (nrows + TPB - 1) / TPB;
    pnn_main<<<grid, TPB, 0, stream>>>(x, cw1, cb1, cb3, hw1, hb1, hw2, hb2, hw3, hb3,
                                       hw4, hb4, hw5, hb5, hw6,
                                       S, dtq, dtp, al, ws, out, nrows);
}

// Round 7
// 377.870 us; speedup vs baseline: 9.1076x; 5.1892x over previous
//
#include <hip/hip_runtime.h>

typedef __attribute__((ext_vector_type(16))) float f32x16;
typedef __attribute__((ext_vector_type(8)))  short bf16x8;
typedef __attribute__((ext_vector_type(2)))  int   i32x2;

// compiler-managed permlane32_swap: a' = {a.lo, b.lo}, b' = {a.hi, b.hi}
__device__ __forceinline__ void laneswap(unsigned& a, unsigned& b){
    i32x2 r = __builtin_amdgcn_permlane32_swap((int)a, (int)b, false, false);
    a = (unsigned)r[0]; b = (unsigned)r[1];
}

// round-to-nearest-even f32 -> bf16
__device__ __forceinline__ unsigned rne16(float x){
    unsigned u = __float_as_uint(x);
    return (u + 0x7FFFu + ((u >> 16) & 1u)) >> 16;
}

// pack two floats into {bf16(lo), bf16(hi)<<16}
__device__ __forceinline__ unsigned cvtpk(float lo, float hi){
    unsigned ul = __float_as_uint(lo);
    unsigned uh = __float_as_uint(hi);
    ul = (ul + 0x7FFFu + ((ul >> 16) & 1u)) >> 16;
    uh = (uh + 0x7FFFu + ((uh >> 16) & 1u)) & 0xFFFF0000u;   // keep in high half
    return ul | uh;
}

__device__ __forceinline__ float halfsum(float v){   // v + (other 32-lane half)
    return v + __shfl_xor(v, 32, 64);
}

__device__ __forceinline__ float fast_tanh(float v){
    float vc = fminf(v, 15.0f);
    float e  = __expf(vc + vc);
    float r  = __builtin_amdgcn_rcpf(e + 1.0f);
    return (e - 1.0f) * r;
}

union U4 { unsigned u[4]; bf16x8 v; };

__device__ __forceinline__ f32x16 zf(){
    f32x16 z;
#pragma unroll
    for (int i=0;i<16;++i) z[i]=0.f;
    return z;
}

__device__ __forceinline__ bf16x8 ldA(const unsigned short* p){
    return *(const bf16x8*)p;   // 16B-aligned ds_read_b128
}

__device__ __forceinline__ f32x16 MF(bf16x8 a, bf16x8 b, f32x16 c){
    return __builtin_amdgcn_mfma_f32_32x32x16_bf16(a, b, c, 0, 0, 0);
}

__device__ __forceinline__ unsigned short tob(float x){
    return (unsigned short)rne16(x);
}

struct alignas(16) SLDS {
    unsigned short cw2T[128*136];   // [i][k] = cw2[k][i]; col 128 = cb2
    unsigned short fwdWT[4][64*72]; // hw2..5: [i][k] = W[k][i]; col 64 = bias
    unsigned short bwdW[4][64*72];  // hw2..5 row-major [k_out][f]
    unsigned short hw1T[64*16];     // [i][k]: k0-3 = hw1[k][i], k4 = hb1[i]
    float c1pack[128*4];            // {cw1[0][k], cw1[1][k], cb1[k], 0}
    float cw3p[128*2];
    float hw1c[64*4];               // {hw1[0][f], hw1[1][f], hw1[2][f], hw1[3][f]}
    float hw6v[64];
    float cb3v[2];
    float pad[30];                  // tail guard (h=1 bias-step overreads see x0 operands)
};
// sizeof = 110592 + 4480 = 115072 B = 7192 uint4

// fwd layer 64->64: D = WT x B over 4 K-steps + bias K-step
__device__ __forceinline__ void fwd64(const unsigned short* W, const unsigned* pkin,
                                      f32x16& A0, f32x16& A1, int col, int h){
    A0 = zf(); A1 = zf();
#pragma unroll
    for (int st=0; st<4; ++st){
        unsigned u0 = pkin[4*st+0], u2 = pkin[4*st+2];
        unsigned u1 = pkin[4*st+1], u3 = pkin[4*st+3];
        laneswap(u0, u2);
        laneswap(u1, u3);
        U4 bu; bu.u[0]=u0; bu.u[1]=u1; bu.u[2]=u2; bu.u[3]=u3;
        const unsigned short* p0 = W + col*72 + st*16 + h*8;
        A0 = MF(ldA(p0),         bu.v, A0);
        A1 = MF(ldA(p0 + 32*72), bu.v, A1);
    }
    U4 bb; bb.u[0] = h ? 0u : 0x3F80u; bb.u[1]=0u; bb.u[2]=0u; bb.u[3]=0u;
    const unsigned short* pb = W + col*72 + 64 + h*8;
    A0 = MF(ldA(pb),         bb.v, A0);
    A1 = MF(ldA(pb + 32*72), bb.v, A1);
}

__device__ __forceinline__ void bwd64(const unsigned short* W, const unsigned* pkin,
                                      f32x16& A0, f32x16& A1, int col, int h){
    A0 = zf(); A1 = zf();
#pragma unroll
    for (int st=0; st<4; ++st){
        unsigned u0 = pkin[4*st+0], u2 = pkin[4*st+2];
        unsigned u1 = pkin[4*st+1], u3 = pkin[4*st+3];
        laneswap(u0, u2);
        laneswap(u1, u3);
        U4 bu; bu.u[0]=u0; bu.u[1]=u1; bu.u[2]=u2; bu.u[3]=u3;
        const unsigned short* p0 = W + col*72 + st*16 + h*8;
        A0 = MF(ldA(p0),         bu.v, A0);
        A1 = MF(ldA(p0 + 32*72), bu.v, A1);
    }
}

__device__ __forceinline__ void relu_pk(const f32x16& z0, const f32x16& z1,
                                        unsigned& mask, unsigned* pk){
    unsigned m = 0u;
#pragma unroll
    for (int i=0;i<8;++i){
        float a = z0[2*i], b = z0[2*i+1];
        if (a > 0.f) m |= 1u << (2*i);   else a = 0.f;
        if (b > 0.f) m |= 1u << (2*i+1); else b = 0.f;
        pk[i] = cvtpk(a, b);
    }
#pragma unroll
    for (int i=0;i<8;++i){
        float a = z1[2*i], b = z1[2*i+1];
        if (a > 0.f) m |= 1u << (16+2*i);   else a = 0.f;
        if (b > 0.f) m |= 1u << (16+2*i+1); else b = 0.f;
        pk[8+i] = cvtpk(a, b);
    }
    mask = m;
}

__device__ __forceinline__ void tanh_pk(const f32x16& z0, const f32x16& z1, unsigned* pk){
#pragma unroll
    for (int i=0;i<8;++i) pk[i]   = cvtpk(fast_tanh(z0[2*i]), fast_tanh(z0[2*i+1]));
#pragma unroll
    for (int i=0;i<8;++i) pk[8+i] = cvtpk(fast_tanh(z1[2*i]), fast_tanh(z1[2*i+1]));
}

__device__ __forceinline__ void repack_pk(const f32x16& g0, const f32x16& g1, unsigned* pk){
#pragma unroll
    for (int i=0;i<8;++i) pk[i]   = cvtpk(g0[2*i], g0[2*i+1]);
#pragma unroll
    for (int i=0;i<8;++i) pk[8+i] = cvtpk(g1[2*i], g1[2*i+1]);
}

// coupling net 2->125(relu)->125(tanh)->2, batch-in-lane-column MFMA form
__device__ __forceinline__ float2 couple(float u0f, float u1f, const SLDS* s, int col, int h){
    f32x16 c0 = zf(), c1 = zf(), c2 = zf(), c3 = zf();
#pragma unroll 2
    for (int st=0; st<8; ++st){
        float hv[8];
#pragma unroll
        for (int e=0; e<8; ++e){
            int k = st*16 + h*8 + e;
            float4 cc = *(const float4*)&s->c1pack[4*k];
            hv[e] = fmaxf(fmaf(u1f, cc.y, fmaf(u0f, cc.x, cc.z)), 0.f);
        }
        U4 bu;
        bu.u[0]=cvtpk(hv[0],hv[1]); bu.u[1]=cvtpk(hv[2],hv[3]);
        bu.u[2]=cvtpk(hv[4],hv[5]); bu.u[3]=cvtpk(hv[6],hv[7]);
        const unsigned short* p = s->cw2T + col*136 + st*16 + h*8;
        c0 = MF(ldA(p),          bu.v, c0);
        c1 = MF(ldA(p + 32*136), bu.v, c1);
        c2 = MF(ldA(p + 64*136), bu.v, c2);
        c3 = MF(ldA(p + 96*136), bu.v, c3);
    }
    {   // bias K-step: B = {1,0,...} on h=0; A cols 128.. hold cb2
        U4 bb; bb.u[0] = h ? 0u : 0x3F80u; bb.u[1]=0u; bb.u[2]=0u; bb.u[3]=0u;
        const unsigned short* p = s->cw2T + col*136 + 128 + h*8;
        c0 = MF(ldA(p),          bb.v, c0);
        c1 = MF(ldA(p + 32*136), bb.v, c1);
        c2 = MF(ldA(p + 64*136), bb.v, c2);
        c3 = MF(ldA(p + 96*136), bb.v, c3);
    }
    float o0 = 0.f, o1 = 0.f;
#define CDOT(CA, T) \
    _Pragma("unroll") \
    for (int r=0; r<16; ++r){ \
        float t = fast_tanh(CA[r]); \
        int f = (T)*32 + (r>>2)*8 + (r&3) + h*4; \
        float2 wv = *(const float2*)&s->cw3p[2*f]; \
        o0 = fmaf(t, wv.x, o0); o1 = fmaf(t, wv.y, o1); }
    CDOT(c0,0) CDOT(c1,1) CDOT(c2,2) CDOT(c3,3)
#undef CDOT
    o0 = halfsum(o0);
    o1 = halfsum(o1);
    return make_float2(o0 + s->cb3v[0], o1 + s->cb3v[1]);
}

// one-shot: build the SLDS image in global workspace
__global__ void pack_ws(const float* __restrict__ cw1, const float* __restrict__ cb1,
                        const float* __restrict__ cw2, const float* __restrict__ cb2,
                        const float* __restrict__ cw3, const float* __restrict__ cb3,
                        const float* __restrict__ hw1, const float* __restrict__ hb1,
                        const float* __restrict__ hw2, const float* __restrict__ hb2,
                        const float* __restrict__ hw3, const float* __restrict__ hb3,
                        const float* __restrict__ hw4, const float* __restrict__ hb4,
                        const float* __restrict__ hw5, const float* __restrict__ hb5,
                        const float* __restrict__ hw6, SLDS* __restrict__ g){
    const int tid = blockIdx.x*256 + threadIdx.x;
    const int NT  = 64*256;
    for (int i = tid; i < 128*136; i += NT){
        int r = i/136, k = i%136;
        float v = 0.f;
        if (k < 125 && r < 125) v = cw2[k*125 + r];
        else if (k == 128 && r < 125) v = cb2[r];
        g->cw2T[i] = tob(v);
    }
#pragma unroll
    for (int m=0; m<4; ++m){
        const float* w = (m==0)?hw2:(m==1)?hw3:(m==2)?hw4:hw5;
        const float* b = (m==0)?hb2:(m==1)?hb3:(m==2)?hb4:hb5;
        for (int i = tid; i < 64*72; i += NT){
            int r = i/72, k = i%72;
            g->fwdWT[m][i] = tob((k<64) ? w[k*64 + r] : ((k==64) ? b[r] : 0.f));
            g->bwdW[m][i]  = tob((k<64) ? w[r*64 + k] : 0.f);
        }
    }
    for (int i = tid; i < 64*16; i += NT){
        int r = i/16, k = i%16;
        g->hw1T[i] = tob((k<4) ? hw1[k*64 + r] : ((k==4) ? hb1[r] : 0.f));
    }
    for (int k = tid; k < 128; k += NT){
        bool in = k < 125;
        g->c1pack[4*k+0] = in ? cw1[k]     : 0.f;
        g->c1pack[4*k+1] = in ? cw1[125+k] : 0.f;
        g->c1pack[4*k+2] = in ? cb1[k]     : 0.f;
        g->c1pack[4*k+3] = 0.f;
        g->cw3p[2*k+0]   = in ? cw3[2*k]   : 0.f;
        g->cw3p[2*k+1]   = in ? cw3[2*k+1] : 0.f;
    }
    for (int f = tid; f < 64; f += NT){
        g->hw1c[4*f+0] = hw1[f];
        g->hw1c[4*f+1] = hw1[64+f];
        g->hw1c[4*f+2] = hw1[128+f];
        g->hw1c[4*f+3] = hw1[192+f];
        g->hw6v[f] = hw6[f];
    }
    if (tid == 0){ g->cb3v[0] = cb3[0]; g->cb3v[1] = cb3[1]; }
    for (int i = tid; i < 30; i += NT) g->pad[i] = 0.f;
}

__global__ __launch_bounds__(512, 2) void pnn_mfma(
    const float* __restrict__ x, const SLDS* __restrict__ g,
    const float* __restrict__ S, const float* __restrict__ dt_q,
    const float* __restrict__ dt_p, const float* __restrict__ alpha_p,
    float* __restrict__ out)
{
    __shared__ SLDS s;
    const int tid = threadIdx.x;

    // stage SLDS image (16B copies)
    {
        const uint4* src = (const uint4*)g;
        uint4* dst = (uint4*)&s;
        for (int i = tid; i < (int)(sizeof(SLDS)/16); i += 512) dst[i] = src[i];
    }
    __syncthreads();

    const int lane = tid & 63;
    const int wv   = tid >> 6;
    const int col  = lane & 31;
    const int h    = lane >> 5;
    const int row  = blockIdx.x * 256 + wv*32 + col;

    float4 xv = ((const float4*)x)[row];

    float2 cpl = couple(xv.x, xv.y, &s, col, h);
    float th0 = xv.x, th1 = xv.y, th2 = xv.z + cpl.x, th3 = xv.w + cpl.y;

    // ---- H forward L1 (theta K=4 + bias slot, one K-step) ----
    f32x16 z0, z1;
    {
        U4 b1;
        b1.u[0] = h ? 0u : cvtpk(th0, th1);
        b1.u[1] = h ? 0u : cvtpk(th2, th3);
        b1.u[2] = h ? 0u : 0x3F80u;
        b1.u[3] = 0u;
        const unsigned short* p = s.hw1T + col*16 + h*8;
        z0 = MF(ldA(p),         b1.v, zf());
        z1 = MF(ldA(p + 32*16), b1.v, zf());
    }

    unsigned m1, m2;
    unsigned pkA[16], pk3[16], pk4[16], pkG[16];
    relu_pk(z0, z1, m1, pkA);

    fwd64(s.fwdWT[0], pkA, z0, z1, col, h);      // L2
    relu_pk(z0, z1, m2, pkA);

    fwd64(s.fwdWT[1], pkA, z0, z1, col, h);      // L3
    tanh_pk(z0, z1, pk3);

    fwd64(s.fwdWT[2], pk3, z0, z1, col, h);      // L4
    tanh_pk(z0, z1, pk4);

    fwd64(s.fwdWT[3], pk4, z0, z1, col, h);      // L5
    // g5 = hw6 ⊙ (1 - tanh(z5)^2)
#define G5T(ZZ, T) \
    _Pragma("unroll") \
    for (int q=0; q<4; ++q){ \
        float4 w6 = *(const float4*)&s.hw6v[(T)*32 + q*8 + h*4]; \
        float t0 = fast_tanh(ZZ[4*q+0]); float g0v = w6.x * fmaf(-t0,t0,1.f); \
        float t1 = fast_tanh(ZZ[4*q+1]); float g1v = w6.y * fmaf(-t1,t1,1.f); \
        float t2 = fast_tanh(ZZ[4*q+2]); float g2v = w6.z * fmaf(-t2,t2,1.f); \
        float t3 = fast_tanh(ZZ[4*q+3]); float g3v = w6.w * fmaf(-t3,t3,1.f); \
        pkG[(T)*8 + 2*q]   = cvtpk(g0v, g1v); \
        pkG[(T)*8 + 2*q+1] = cvtpk(g2v, g3v); }
    G5T(z0, 0)
    G5T(z1, 1)
#undef G5T

    // ---- backward ----
    f32x16 g0, g1;
#define TPRIME(PK) \
    _Pragma("unroll") \
    for (int i=0;i<8;++i){ \
        float tl = __uint_as_float(PK[i] << 16); \
        float tH = __uint_as_float(PK[i] & 0xFFFF0000u); \
        g0[2*i]   *= fmaf(-tl, tl, 1.f); \
        g0[2*i+1] *= fmaf(-tH, tH, 1.f); } \
    _Pragma("unroll") \
    for (int i=0;i<8;++i){ \
        float tl = __uint_as_float(PK[8+i] << 16); \
        float tH = __uint_as_float(PK[8+i] & 0xFFFF0000u); \
        g1[2*i]   *= fmaf(-tl, tl, 1.f); \
        g1[2*i+1] *= fmaf(-tH, tH, 1.f); }

    bwd64(s.bwdW[3], pkG, g0, g1, col, h);       // g4
    TPRIME(pk4)
    repack_pk(g0, g1, pkG);

    bwd64(s.bwdW[2], pkG, g0, g1, col, h);       // g3
    TPRIME(pk3)
    repack_pk(g0, g1, pkG);

    bwd64(s.bwdW[1], pkG, g0, g1, col, h);       // g2
#pragma unroll
    for (int r=0;r<16;++r){
        if (!((m2 >> r) & 1u))      g0[r] = 0.f;
        if (!((m2 >> (16+r)) & 1u)) g1[r] = 0.f;
    }
    repack_pk(g0, g1, pkG);

    bwd64(s.bwdW[0], pkG, g0, g1, col, h);       // g1
#pragma unroll
    for (int r=0;r<16;++r){
        if (!((m1 >> r) & 1u))      g0[r] = 0.f;
        if (!((m1 >> (16+r)) & 1u)) g1[r] = 0.f;
    }
#undef TPRIME

    // dH = g1 @ hw1^T: per-lane partial over its 32 features, then cross-half add
    float dh0=0.f, dh1=0.f, dh2=0.f, dh3=0.f;
#define DHT(GG, T) \
    _Pragma("unroll") \
    for (int q=0;q<4;++q){ \
        int f0 = (T)*32 + q*8 + h*4; \
        _Pragma("unroll") \
        for (int m=0;m<4;++m){ \
            float4 wv4 = *(const float4*)&s.hw1c[4*(f0+m)]; \
            float gv = GG[4*q+m]; \
            dh0 = fmaf(gv, wv4.x, dh0); dh1 = fmaf(gv, wv4.y, dh1); \
            dh2 = fmaf(gv, wv4.z, dh2); dh3 = fmaf(gv, wv4.w, dh3); } }
    DHT(g0, 0)
    DHT(g1, 1)
#undef DHT
    dh0 = halfsum(dh0);
    dh1 = halfsum(dh1);
    dh2 = halfsum(dh2);
    dh3 = halfsum(dh3);

    // ---- epilogue ----
    float s01 = S[1] - S[4],  s02 = S[2]  - S[8],  s03 = S[3]  - S[12];
    float s10 = -s01,         s12 = S[6]  - S[9],  s13 = S[7]  - S[13];
    float s23 = S[11] - S[14];
    float s32 = -s23;

    float al = alpha_p[0], dq = dt_q[0], dp = dt_p[0];
    float r10 = th1 * s01 + th2 * s02 + th3 * s03;
    float r11 = th0 * s10 + th2 * s12 + th3 * s13;
    float r20 = th0 * s02 + th1 * s12 + th3 * s32;
    float r21 = th0 * s03 + th1 * s13 + th2 * s23;

    float dz10 =  dh2 * dq + al * r10;
    float dz11 =  dh3 * dq + al * r11;
    float dz20 = -dh0 * dp + al * r20;
    float dz21 = -dh1 * dp + al * r21;

    float p0 = th0 + 0.1f * dz10;
    float p1 = th1 + 0.1f * dz11;
    float p2 = th2 + 0.1f * dz20;
    float p3 = th3 + 0.1f * dz21;

    float2 d = couple(p0, p1, &s, col, h);

    if (h == 0)
        ((float4*)out)[row] = make_float4(p0, p1, p2 - d.x, p3 - d.y);
}

extern "C" void kernel_launch(void* const* d_in, const int* in_sizes, int n_in,
                              void* d_out, int out_size, void* d_ws, size_t ws_size,
                              hipStream_t stream) {
    (void)n_in; (void)out_size; (void)ws_size;
    const float* x   = (const float*)d_in[0];
    const float* cw1 = (const float*)d_in[1];
    const float* cb1 = (const float*)d_in[2];
    const float* cw2 = (const float*)d_in[3];
    const float* cb2 = (const float*)d_in[4];
    const float* cw3 = (const float*)d_in[5];
    const float* cb3 = (const float*)d_in[6];
    const float* hw1 = (const float*)d_in[7];
    const float* hb1 = (const float*)d_in[8];
    const float* hw2 = (const float*)d_in[9];
    const float* hb2 = (const float*)d_in[10];
    const float* hw3 = (const float*)d_in[11];
    const float* hb3 = (const float*)d_in[12];
    const float* hw4 = (const float*)d_in[13];
    const float* hb4 = (const float*)d_in[14];
    const float* hw5 = (const float*)d_in[15];
    const float* hb5 = (const float*)d_in[16];
    const float* hw6 = (const float*)d_in[17];
    const float* S   = (const float*)d_in[19];
    const float* dtq = (const float*)d_in[20];
    const float* dtp = (const float*)d_in[21];
    const float* al  = (const float*)d_in[22];
    float* out = (float*)d_out;
    SLDS* g   = (SLDS*)d_ws;
    int nrows = in_sizes[0] / 4;
    int grid  = nrows / 256;          // B = 524288 -> 2048 exact

    pack_ws<<<64, 256, 0, stream>>>(cw1, cb1, cw2, cb2, cw3, cb3, hw1, hb1,
                                    hw2, hb2, hw3, hb3, hw4, hb4, hw5, hb5, hw6, g);
    pnn_mfma<<<grid, 512, 0, stream>>>(x, g, S, dtq, dtp, al, out);
}